// Round 18
// baseline (408.923 us; speedup 1.0000x reference)
//
#include <hip/hip_runtime.h>
#include <math.h>

#define HDIM  512
#define NSAMP 128
#define NN    400
#define NN2   160000  // 400*400
#define KZERO 48000   // int(400*400*30/100)
#define NROWS 51200   // 128*400
#define TIECAP 4096

// XLA:CPU f32 exp: Cephes polynomial (GenerateVF32Exp) on an FMA host with
// AllowFPOpFusion::Fast: floor(fma(x,log2e,0.5)); fused Cody-Waite (vfnmadd);
// FMA Horner; y = fma(y,x*x,x)+1; exact 2^n. For boundary elements
// (|z|<0.34) fx=0 and the value is the pure FMA-Horner rational.
__device__ __forceinline__ float xla_expf(float x) {
  x = fminf(88.3762626647950f, fmaxf(-88.3762626647949f, x));
  float fx = floorf(fmaf(x, 1.44269504088896341f, 0.5f));
  x = fmaf(fx, -0.693359375f, x);       // fused: x - fx*C1
  x = fmaf(fx, 2.12194440e-4f, x);      // fused: x - fx*C2
  float z2 = __fmul_rn(x, x);
  float y = 1.9875691500e-4f;
  y = fmaf(y, x, 1.3981999507e-3f);
  y = fmaf(y, x, 8.3334519073e-3f);
  y = fmaf(y, x, 4.1665795894e-2f);
  y = fmaf(y, x, 1.6666665459e-1f);
  y = fmaf(y, x, 5.0000001201e-1f);
  y = fmaf(y, z2, x);
  y = __fadd_rn(y, 1.0f);
  int n = (int)fx;                               // fx integral: trunc exact
  float p2n = __int_as_float((n + 127) << 23);   // exact 2^n
  return __fmul_rn(y, p2n);
}

// XLA LogisticExpander (exp form): logistic(z) = 1/(1+exp(-z)), strict f32,
// IEEE divide.
__device__ __forceinline__ float sigf(float g, float m) {
  float z = __fmul_rn(g, m);
  float e = xla_expf(-z);
  float den = __fadd_rn(1.0f, e);
  return __fdiv_rn(1.0f, den);
}

// One wave64 per row of 512: copy row to out0, f32 max (order-free), and the
// XLA:CPU IrEmitter vectorized reduce at 256-bit width: ONE v8f32 accumulator
// (IC=1): A[j] = sum_{t=0..63} p[8t+j] (sequential t), then reassoc
// vector.reduce.fadd halving tree: (j,j+4),(j,j+2),(j,j+1).
// 512 = 8*64 exactly -> no epilogue. mean = S/512 (exact pow2).
__global__ __launch_bounds__(256) void k_pool(const float* __restrict__ x,
                                              float* __restrict__ out0,
                                              float* __restrict__ glb,
                                              float* __restrict__ mx) {
  __shared__ float buf[4][512];
  const int wave = threadIdx.x >> 6;
  const int lane = threadIdx.x & 63;
  const int row  = blockIdx.x * 4 + wave;
  const float4* xr = reinterpret_cast<const float4*>(x) + (size_t)row * 128;
  float4* o = reinterpret_cast<float4*>(out0) + (size_t)row * 128;
  float4 a = xr[lane];
  float4 b = xr[lane + 64];
  o[lane]      = a;
  o[lane + 64] = b;
  reinterpret_cast<float4*>(buf[wave])[lane]      = a;
  reinterpret_cast<float4*>(buf[wave])[lane + 64] = b;
  float m = fmaxf(fmaxf(fmaxf(a.x, a.y), fmaxf(a.z, a.w)),
                  fmaxf(fmaxf(b.x, b.y), fmaxf(b.z, b.w)));
#pragma unroll
  for (int off = 32; off > 0; off >>= 1) m = fmaxf(m, __shfl_xor(m, off));
  __syncthreads();
  float r = 0.0f;
  if (lane < 8) {
    const float* p = buf[wave] + lane;
    r = p[0];
    for (int t = 1; t < 64; ++t) r = __fadd_rn(r, p[8 * t]);  // sequential t
    // llvm.vector.reduce.fadd halving tree over v8
    r = __fadd_rn(r, __shfl_xor(r, 4));
    r = __fadd_rn(r, __shfl_xor(r, 2));
    r = __fadd_rn(r, __shfl_xor(r, 1));
  }
  if (lane == 0) {
    glb[row] = __fmul_rn(r, 0.001953125f);  // *1/512, exact pow2
    mx[row]  = m;
  }
}

// One block per sample: exact rank-48000 selection on key = (bits(sigmoid_f32),
// index) via 4-round MSB radix select (sigmoid > 0 so raw-bit order == float
// order), stable smallest-index-first within the threshold tie group.
__global__ __launch_bounds__(1024) void k_select(const float* __restrict__ glb,
                                                 const float* __restrict__ mx,
                                                 float* __restrict__ adj) {
  const int b   = blockIdx.x;
  const int tid = threadIdx.x;

  __shared__ float g[NN];
  __shared__ float mm[NN];
  __shared__ unsigned int hist[256];
  __shared__ unsigned int shT;
  __shared__ unsigned int shR;
  __shared__ unsigned int tiecnt;
  __shared__ int tie[TIECAP];
  __shared__ int shIdxT;

  for (int i = tid; i < NN; i += 1024) {
    g[i]  = glb[(size_t)b * NN + i];
    mm[i] = mx[(size_t)b * NN + i];
  }
  if (tid == 0) { shT = 0u; shR = KZERO; shIdxT = NN2; }
  __syncthreads();

  for (int round = 0; round < 4; ++round) {
    for (int i = tid; i < 256; i += 1024) hist[i] = 0u;
    __syncthreads();
    const unsigned int pre = shT;
    const int sh = 24 - 8 * round;
    for (int e = tid; e < NN2; e += 1024) {
      int i = e / NN;
      int j2 = e - i * NN;
      unsigned int u = __float_as_uint(sigf(g[i], mm[j2]));
      bool cand = (round == 0) || ((u >> (sh + 8)) == pre);
      if (cand) atomicAdd(&hist[(u >> sh) & 255u], 1u);
    }
    __syncthreads();
    if (tid == 0) {
      unsigned int rr = shR, cum = 0u;
      int d = 0;
      for (; d < 256; ++d) {
        unsigned int cnt = hist[d];
        if (cum + cnt > rr) break;
        cum += cnt;
      }
      shT = (pre << 8) | (unsigned int)d;
      shR = rr - cum;
    }
    __syncthreads();
  }

  const unsigned int T = shT;   // key at rank 48000 (first kept key value)
  if (tid == 0) tiecnt = 0u;
  __syncthreads();

  for (int e = tid; e < NN2; e += 1024) {
    int i = e / NN;
    int j2 = e - i * NN;
    if (__float_as_uint(sigf(g[i], mm[j2])) == T) {
      unsigned int pos = atomicAdd(&tiecnt, 1u);
      if (pos < TIECAP) tie[pos] = e;
    }
  }
  __syncthreads();
  const int n = (int)(tiecnt < TIECAP ? tiecnt : TIECAP);
  const unsigned int rtarget = shR;  // # of T-ties to zero (smallest indices)
  for (int i = tid; i < n; i += 1024) {
    int v = tie[i];
    unsigned int rank = 0;
    for (int j2 = 0; j2 < n; ++j2) rank += (unsigned)(tie[j2] < v);
    if (rank == rtarget) shIdxT = v;
  }
  __syncthreads();
  const int idxT = shIdxT;

  for (int e = tid; e < NN2; e += 1024) {
    int i = e / NN;
    int j2 = e - i * NN;
    float s = sigf(g[i], mm[j2]);
    unsigned int u = __float_as_uint(s);
    bool z = (u < T) || (u == T && e < idxT);
    adj[(size_t)b * NN2 + e] = z ? 0.0f : s;
  }
}

extern "C" void kernel_launch(void* const* d_in, const int* in_sizes, int n_in,
                              void* d_out, int out_size, void* d_ws, size_t ws_size,
                              hipStream_t stream) {
  const float* x = (const float*)d_in[0];
  float* out0 = (float*)d_out;                     // xf: 26,214,400 floats
  float* adj  = (float*)d_out + (size_t)26214400;  // dynamic_ftr_map: 20,480,000 floats

  float* glb = (float*)d_ws;
  float* mx  = (float*)d_ws + NROWS;

  k_pool<<<NROWS / 4, 256, 0, stream>>>(x, out0, glb, mx);
  k_select<<<NSAMP, 1024, 0, stream>>>(glb, mx, adj);
}

// Round 19
// 199.665 us; speedup vs baseline: 2.0480x; 2.0480x over previous
//
#include <hip/hip_runtime.h>
#include <math.h>

#define HDIM  512
#define NSAMP 128
#define NN    400
#define NN2   160000  // 400*400
#define KZERO 48000   // int(400*400*30/100)
#define NROWS 51200   // 128*400
#define BPS   5       // blocks per sample in element-sweep kernels
#define QPS   40000   // uint4 quads per sample (160000/4)
#define QPB   8000    // quads per block (QPS/BPS)
#define CANDCAP 512

// ===== FROZEN bit-exact math (verified PASS in round 18) =====
// XLA:CPU Cephes exp, fully FMA-contracted.
__device__ __forceinline__ float xla_expf(float x) {
  x = fminf(88.3762626647950f, fmaxf(-88.3762626647949f, x));
  float fx = floorf(fmaf(x, 1.44269504088896341f, 0.5f));
  x = fmaf(fx, -0.693359375f, x);
  x = fmaf(fx, 2.12194440e-4f, x);
  float z2 = __fmul_rn(x, x);
  float y = 1.9875691500e-4f;
  y = fmaf(y, x, 1.3981999507e-3f);
  y = fmaf(y, x, 8.3334519073e-3f);
  y = fmaf(y, x, 4.1665795894e-2f);
  y = fmaf(y, x, 1.6666665459e-1f);
  y = fmaf(y, x, 5.0000001201e-1f);
  y = fmaf(y, z2, x);
  y = __fadd_rn(y, 1.0f);
  int n = (int)fx;
  float p2n = __int_as_float((n + 127) << 23);
  return __fmul_rn(y, p2n);
}

__device__ __forceinline__ float sigf(float g, float m) {
  float z = __fmul_rn(g, m);
  float e = xla_expf(-z);
  float den = __fadd_rn(1.0f, e);
  return __fdiv_rn(1.0f, den);
}

// k_pool: FROZEN (copy + order-free max + VF8xIC1 mean).
__global__ __launch_bounds__(256) void k_pool(const float* __restrict__ x,
                                              float* __restrict__ out0,
                                              float* __restrict__ glb,
                                              float* __restrict__ mx) {
  __shared__ float buf[4][512];
  const int wave = threadIdx.x >> 6;
  const int lane = threadIdx.x & 63;
  const int row  = blockIdx.x * 4 + wave;
  const float4* xr = reinterpret_cast<const float4*>(x) + (size_t)row * 128;
  float4* o = reinterpret_cast<float4*>(out0) + (size_t)row * 128;
  float4 a = xr[lane];
  float4 b = xr[lane + 64];
  o[lane]      = a;
  o[lane + 64] = b;
  reinterpret_cast<float4*>(buf[wave])[lane]      = a;
  reinterpret_cast<float4*>(buf[wave])[lane + 64] = b;
  float m = fmaxf(fmaxf(fmaxf(a.x, a.y), fmaxf(a.z, a.w)),
                  fmaxf(fmaxf(b.x, b.y), fmaxf(b.z, b.w)));
#pragma unroll
  for (int off = 32; off > 0; off >>= 1) m = fmaxf(m, __shfl_xor(m, off));
  __syncthreads();
  float r = 0.0f;
  if (lane < 8) {
    const float* p = buf[wave] + lane;
    r = p[0];
    for (int t = 1; t < 64; ++t) r = __fadd_rn(r, p[8 * t]);
    r = __fadd_rn(r, __shfl_xor(r, 4));
    r = __fadd_rn(r, __shfl_xor(r, 2));
    r = __fadd_rn(r, __shfl_xor(r, 1));
  }
  if (lane == 0) {
    glb[row] = __fmul_rn(r, 0.001953125f);
    mx[row]  = m;
  }
}

// ===== Pipeline =====

// zero per-sample state + histograms
__global__ __launch_bounds__(256) void k_init(unsigned int* __restrict__ hist,
                                              unsigned int* __restrict__ stT,
                                              unsigned int* __restrict__ stR,
                                              int* __restrict__ stIdxT,
                                              unsigned int* __restrict__ stNC) {
  int b = blockIdx.x, t = threadIdx.x;
  hist[b * 256 + t] = 0u;
  if (t == 0) { stT[b] = 0u; stR[b] = KZERO; stIdxT[b] = NN2; stNC[b] = 0u; }
}

// compute each sigmoid ONCE, store bits to adj, build round-0 (top byte) hist
__global__ __launch_bounds__(256) void k_sig(const float* __restrict__ glb,
                                             const float* __restrict__ mx,
                                             unsigned int* __restrict__ adju,
                                             unsigned int* __restrict__ hist) {
  const int blk = blockIdx.x, b = blk / BPS, part = blk % BPS, t = threadIdx.x;
  __shared__ unsigned int lh[256];
  lh[t] = 0u;
  __syncthreads();
  const float* gb = glb + b * NN;
  const float4* mb = (const float4*)(mx + b * NN);
  uint4* base = (uint4*)adju + (size_t)b * QPS;
  const int qend = (part + 1) * QPB;
  for (int q = part * QPB + t; q < qend; q += 256) {
    int i  = q / 100;            // 100 quads per row
    int jq = q - i * 100;        // quad within row
    float g = gb[i];
    float4 m4 = mb[jq];
    uint4 u;
    u.x = __float_as_uint(sigf(g, m4.x));
    u.y = __float_as_uint(sigf(g, m4.y));
    u.z = __float_as_uint(sigf(g, m4.z));
    u.w = __float_as_uint(sigf(g, m4.w));
    base[q] = u;
    unsigned d0 = u.x >> 24, d1 = u.y >> 24, d2 = u.z >> 24, d3 = u.w >> 24;
    if (d0 == d1 && d1 == d2 && d2 == d3) {
      atomicAdd(&lh[d0], 4u);
    } else {
      atomicAdd(&lh[d0], 1u); atomicAdd(&lh[d1], 1u);
      atomicAdd(&lh[d2], 1u); atomicAdd(&lh[d3], 1u);
    }
  }
  __syncthreads();
  if (lh[t]) atomicAdd(&hist[b * 256 + t], lh[t]);
}

// radix histogram pass for rounds with shift sh (16, 8, 0). sh==0 also
// captures candidates (elements matching the 24-bit prefix).
__global__ __launch_bounds__(256) void k_hist(const unsigned int* __restrict__ adju,
                                              unsigned int* __restrict__ hist,
                                              const unsigned int* __restrict__ stT,
                                              unsigned int* __restrict__ stNC,
                                              unsigned int* __restrict__ candI,
                                              unsigned int* __restrict__ candU,
                                              int sh) {
  const int blk = blockIdx.x, b = blk / BPS, part = blk % BPS, t = threadIdx.x;
  __shared__ unsigned int lh[256];
  lh[t] = 0u;
  __syncthreads();
  const unsigned int pre = stT[b];
  const uint4* base = (const uint4*)adju + (size_t)b * QPS;
  const int qend = (part + 1) * QPB;
  for (int q = part * QPB + t; q < qend; q += 256) {
    uint4 u = base[q];
    unsigned int uv[4] = {u.x, u.y, u.z, u.w};
#pragma unroll
    for (int k = 0; k < 4; ++k) {
      unsigned int uu = uv[k];
      if ((uu >> (sh + 8)) == pre) {
        atomicAdd(&lh[(uu >> sh) & 255u], 1u);
        if (sh == 0) {
          unsigned int pos = atomicAdd(&stNC[b], 1u);
          if (pos < CANDCAP) {
            candI[b * CANDCAP + pos] = (unsigned)(q * 4 + k);
            candU[b * CANDCAP + pos] = uu;
          }
        }
      }
    }
  }
  __syncthreads();
  if (lh[t]) atomicAdd(&hist[b * 256 + t], lh[t]);
}

// per-sample digit selection; round<3 re-zeroes hist; round 3 resolves the
// stable tie index from the candidate list.
__global__ __launch_bounds__(256) void k_scan(unsigned int* __restrict__ hist,
                                              unsigned int* __restrict__ stT,
                                              unsigned int* __restrict__ stR,
                                              int* __restrict__ stIdxT,
                                              const unsigned int* __restrict__ stNC,
                                              const unsigned int* __restrict__ candI,
                                              const unsigned int* __restrict__ candU,
                                              int round) {
  const int b = blockIdx.x, t = threadIdx.x;
  __shared__ unsigned int h[256];
  __shared__ unsigned int shT, shR;
  h[t] = hist[b * 256 + t];
  if (round < 3) hist[b * 256 + t] = 0u;
  __syncthreads();
  if (t == 0) {
    unsigned int rr = stR[b], cum = 0u;
    int d = 0;
    for (; d < 256; ++d) {
      unsigned int c = h[d];
      if (cum + c > rr) break;
      cum += c;
    }
    shT = (stT[b] << 8) | (unsigned int)d;
    shR = rr - cum;
    stT[b] = shT;
    stR[b] = shR;
  }
  __syncthreads();
  if (round == 3) {
    const unsigned int T = shT, R = shR;
    int nc = (int)stNC[b];
    if (nc > CANDCAP) nc = CANDCAP;
    for (int i = t; i < nc; i += 256) {
      unsigned int u = candU[b * CANDCAP + i];
      if (u != T) continue;
      unsigned int myIdx = candI[b * CANDCAP + i];
      unsigned int rank = 0;
      for (int j = 0; j < nc; ++j)
        rank += (unsigned)(candU[b * CANDCAP + j] == T &&
                           candI[b * CANDCAP + j] < myIdx);
      if (rank == R) stIdxT[b] = (int)myIdx;
    }
  }
}

// final in-place rewrite: adj[e] = (key below threshold) ? 0 : sigmoid
__global__ __launch_bounds__(256) void k_final(unsigned int* __restrict__ adju,
                                               const unsigned int* __restrict__ stT,
                                               const int* __restrict__ stIdxT) {
  const int blk = blockIdx.x, b = blk / BPS, part = blk % BPS, t = threadIdx.x;
  const unsigned int T = stT[b];
  const int idxT = stIdxT[b];
  uint4* base = (uint4*)adju + (size_t)b * QPS;
  const int qend = (part + 1) * QPB;
  for (int q = part * QPB + t; q < qend; q += 256) {
    uint4 u = base[q];
    int e0 = q * 4;
    u.x = (u.x < T || (u.x == T && (e0 + 0) < idxT)) ? 0u : u.x;
    u.y = (u.y < T || (u.y == T && (e0 + 1) < idxT)) ? 0u : u.y;
    u.z = (u.z < T || (u.z == T && (e0 + 2) < idxT)) ? 0u : u.z;
    u.w = (u.w < T || (u.w == T && (e0 + 3) < idxT)) ? 0u : u.w;
    base[q] = u;
  }
}

extern "C" void kernel_launch(void* const* d_in, const int* in_sizes, int n_in,
                              void* d_out, int out_size, void* d_ws, size_t ws_size,
                              hipStream_t stream) {
  const float* x = (const float*)d_in[0];
  float* out0 = (float*)d_out;                       // xf: 26,214,400 floats
  unsigned int* adju = (unsigned int*)((float*)d_out + (size_t)26214400);

  char* ws = (char*)d_ws;
  float* glb = (float*)(ws + 0);                      // 51200 f32
  float* mx  = (float*)(ws + 204800);                 // 51200 f32
  unsigned int* hist = (unsigned int*)(ws + 409600);  // [128][256] u32
  unsigned int* stT  = (unsigned int*)(ws + 540672);  // [128]
  unsigned int* stR  = stT + NSAMP;
  int*          stIdxT = (int*)(stR + NSAMP);
  unsigned int* stNC = (unsigned int*)(stIdxT + NSAMP);
  unsigned int* candI = (unsigned int*)(ws + 542720); // [128][512]
  unsigned int* candU = candI + NSAMP * CANDCAP;      // [128][512]  (ends ~1.02 MB)

  k_pool<<<NROWS / 4, 256, 0, stream>>>(x, out0, glb, mx);
  k_init<<<NSAMP, 256, 0, stream>>>(hist, stT, stR, stIdxT, stNC);
  k_sig<<<NSAMP * BPS, 256, 0, stream>>>(glb, mx, adju, hist);
  k_scan<<<NSAMP, 256, 0, stream>>>(hist, stT, stR, stIdxT, stNC, candI, candU, 0);
  k_hist<<<NSAMP * BPS, 256, 0, stream>>>(adju, hist, stT, stNC, candI, candU, 16);
  k_scan<<<NSAMP, 256, 0, stream>>>(hist, stT, stR, stIdxT, stNC, candI, candU, 1);
  k_hist<<<NSAMP * BPS, 256, 0, stream>>>(adju, hist, stT, stNC, candI, candU, 8);
  k_scan<<<NSAMP, 256, 0, stream>>>(hist, stT, stR, stIdxT, stNC, candI, candU, 2);
  k_hist<<<NSAMP * BPS, 256, 0, stream>>>(adju, hist, stT, stNC, candI, candU, 0);
  k_scan<<<NSAMP, 256, 0, stream>>>(hist, stT, stR, stIdxT, stNC, candI, candU, 3);
  k_final<<<NSAMP * BPS, 256, 0, stream>>>(adju, stT, stIdxT);
}

// Round 20
// 174.871 us; speedup vs baseline: 2.3384x; 1.1418x over previous
//
#include <hip/hip_runtime.h>
#include <math.h>

#define HDIM  512
#define NSAMP 128
#define NN    400
#define NN2   160000  // 400*400
#define KZERO 48000   // int(400*400*30/100)
#define NROWS 51200   // 128*400
#define BPS   10      // blocks per sample in element-sweep kernels
#define QPS   40000   // uint4 quads per sample (160000/4)
#define QPB   4000    // quads per block (QPS/BPS)
#define CANDCAP 512

// ===== FROZEN bit-exact math (verified PASS rounds 18/19) =====
__device__ __forceinline__ float xla_expf(float x) {
  x = fminf(88.3762626647950f, fmaxf(-88.3762626647949f, x));
  float fx = floorf(fmaf(x, 1.44269504088896341f, 0.5f));
  x = fmaf(fx, -0.693359375f, x);
  x = fmaf(fx, 2.12194440e-4f, x);
  float z2 = __fmul_rn(x, x);
  float y = 1.9875691500e-4f;
  y = fmaf(y, x, 1.3981999507e-3f);
  y = fmaf(y, x, 8.3334519073e-3f);
  y = fmaf(y, x, 4.1665795894e-2f);
  y = fmaf(y, x, 1.6666665459e-1f);
  y = fmaf(y, x, 5.0000001201e-1f);
  y = fmaf(y, z2, x);
  y = __fadd_rn(y, 1.0f);
  int n = (int)fx;
  float p2n = __int_as_float((n + 127) << 23);
  return __fmul_rn(y, p2n);
}

__device__ __forceinline__ float sigf(float g, float m) {
  float z = __fmul_rn(g, m);
  float e = xla_expf(-z);
  float den = __fadd_rn(1.0f, e);
  return __fdiv_rn(1.0f, den);
}

// k_pool: FROZEN math (copy + order-free max + VF8xIC1 mean) + zeroing of the
// histogram/state region (kernel-boundary ordering makes this safe).
__global__ __launch_bounds__(256) void k_pool(const float* __restrict__ x,
                                              float* __restrict__ out0,
                                              float* __restrict__ glb,
                                              float* __restrict__ mx,
                                              unsigned int* __restrict__ zbase,
                                              int zwords) {
  int gid = blockIdx.x * 256 + threadIdx.x;
  if (gid < zwords) zbase[gid] = 0u;
  __shared__ float buf[4][512];
  const int wave = threadIdx.x >> 6;
  const int lane = threadIdx.x & 63;
  const int row  = blockIdx.x * 4 + wave;
  const float4* xr = reinterpret_cast<const float4*>(x) + (size_t)row * 128;
  float4* o = reinterpret_cast<float4*>(out0) + (size_t)row * 128;
  float4 a = xr[lane];
  float4 b = xr[lane + 64];
  o[lane]      = a;
  o[lane + 64] = b;
  reinterpret_cast<float4*>(buf[wave])[lane]      = a;
  reinterpret_cast<float4*>(buf[wave])[lane + 64] = b;
  float m = fmaxf(fmaxf(fmaxf(a.x, a.y), fmaxf(a.z, a.w)),
                  fmaxf(fmaxf(b.x, b.y), fmaxf(b.z, b.w)));
#pragma unroll
  for (int off = 32; off > 0; off >>= 1) m = fmaxf(m, __shfl_xor(m, off));
  __syncthreads();
  float r = 0.0f;
  if (lane < 8) {
    const float* p = buf[wave] + lane;
    r = p[0];
    for (int t = 1; t < 64; ++t) r = __fadd_rn(r, p[8 * t]);
    r = __fadd_rn(r, __shfl_xor(r, 4));
    r = __fadd_rn(r, __shfl_xor(r, 2));
    r = __fadd_rn(r, __shfl_xor(r, 1));
  }
  if (lane == 0) {
    glb[row] = __fmul_rn(r, 0.001953125f);
    mx[row]  = m;
  }
}

// Parallel digit-select over an nbins histogram (256 threads): finds digit d
// with cum(<d) <= R < cum(<=d), returns (d, R - cum(<d)). Deterministic,
// safe to run redundantly in every block.
__device__ __forceinline__ void scan_select(const unsigned int* __restrict__ h,
                                            int nbins, unsigned int R,
                                            int* d_out, unsigned int* R_out) {
  const int t = threadIdx.x;
  const int lane = t & 63, wid = t >> 6;
  const int nb = nbins >> 8;              // bins per thread (8 or 4)
  unsigned int vals[8];
  unsigned int part = 0;
  for (int k = 0; k < nb; ++k) { vals[k] = h[t * nb + k]; part += vals[k]; }
  unsigned int inc = part;
  for (int off = 1; off < 64; off <<= 1) {
    unsigned int v = __shfl_up(inc, off);
    if (lane >= off) inc += v;
  }
  __shared__ unsigned int wsum[4], bbase[4];
  __shared__ int sd;
  __shared__ unsigned int sR;
  __syncthreads();                         // protect shared reuse across calls
  if (lane == 63) wsum[wid] = inc;
  __syncthreads();
  if (t == 0) {
    unsigned int c = 0;
    for (int w = 0; w < 4; ++w) { bbase[w] = c; c += wsum[w]; }
  }
  __syncthreads();
  unsigned int excl = bbase[wid] + inc - part;
  if (part > 0 && R >= excl && R < excl + part) {
    unsigned int c = excl;
    for (int k = 0; k < nb; ++k) {
      if (R < c + vals[k]) { sd = t * nb + k; sR = R - c; break; }
      c += vals[k];
    }
  }
  __syncthreads();
  *d_out = sd;
  *R_out = sR;
}

// compute each sigmoid ONCE, store bits, build top-11-bit histogram
__global__ __launch_bounds__(256) void k_sig(const float* __restrict__ glb,
                                             const float* __restrict__ mx,
                                             unsigned int* __restrict__ adju,
                                             unsigned int* __restrict__ hist0) {
  const int blk = blockIdx.x, b = blk / BPS, part = blk % BPS, t = threadIdx.x;
  __shared__ unsigned int lh[2048];
  for (int k = t; k < 2048; k += 256) lh[k] = 0u;
  __syncthreads();
  const float* gb = glb + b * NN;
  const float4* mb = (const float4*)(mx + b * NN);
  uint4* base = (uint4*)adju + (size_t)b * QPS;
  const int qend = (part + 1) * QPB;
  for (int q = part * QPB + t; q < qend; q += 256) {
    int i  = q / 100;            // 100 quads per row
    int jq = q - i * 100;
    float g = gb[i];
    float4 m4 = mb[jq];
    uint4 u;
    u.x = __float_as_uint(sigf(g, m4.x));
    u.y = __float_as_uint(sigf(g, m4.y));
    u.z = __float_as_uint(sigf(g, m4.z));
    u.w = __float_as_uint(sigf(g, m4.w));
    base[q] = u;
    atomicAdd(&lh[u.x >> 21], 1u);
    atomicAdd(&lh[u.y >> 21], 1u);
    atomicAdd(&lh[u.z >> 21], 1u);
    atomicAdd(&lh[u.w >> 21], 1u);
  }
  __syncthreads();
  for (int k = t; k < 2048; k += 256)
    if (lh[k]) atomicAdd(&hist0[b * 2048 + k], lh[k]);
}

// round 1: elements matching top-11-bit digit, histogram bits[10..20]
__global__ __launch_bounds__(256) void k_hist1(const unsigned int* __restrict__ adju,
                                               const unsigned int* __restrict__ hist0,
                                               unsigned int* __restrict__ hist2) {
  const int blk = blockIdx.x, b = blk / BPS, part = blk % BPS, t = threadIdx.x;
  int d0; unsigned int R1;
  scan_select(hist0 + b * 2048, 2048, KZERO, &d0, &R1);
  __shared__ unsigned int lh[2048];
  for (int k = t; k < 2048; k += 256) lh[k] = 0u;
  __syncthreads();
  const unsigned int p11 = (unsigned int)d0;
  const uint4* base = (const uint4*)adju + (size_t)b * QPS;
  const int qend = (part + 1) * QPB;
  for (int q = part * QPB + t; q < qend; q += 256) {
    uint4 u = base[q];
    if ((u.x >> 21) == p11) atomicAdd(&lh[(u.x >> 10) & 2047u], 1u);
    if ((u.y >> 21) == p11) atomicAdd(&lh[(u.y >> 10) & 2047u], 1u);
    if ((u.z >> 21) == p11) atomicAdd(&lh[(u.z >> 10) & 2047u], 1u);
    if ((u.w >> 21) == p11) atomicAdd(&lh[(u.w >> 10) & 2047u], 1u);
  }
  __syncthreads();
  for (int k = t; k < 2048; k += 256)
    if (lh[k]) atomicAdd(&hist2[b * 2048 + k], lh[k]);
}

// round 2: elements matching 22-bit prefix, histogram low 10 bits + candidates
__global__ __launch_bounds__(256) void k_hist2(const unsigned int* __restrict__ adju,
                                               const unsigned int* __restrict__ hist0,
                                               const unsigned int* __restrict__ hist2,
                                               unsigned int* __restrict__ hist3,
                                               unsigned int* __restrict__ stNC,
                                               unsigned int* __restrict__ candI,
                                               unsigned int* __restrict__ candU) {
  const int blk = blockIdx.x, b = blk / BPS, part = blk % BPS, t = threadIdx.x;
  int d0, d1; unsigned int R1, R2;
  scan_select(hist0 + b * 2048, 2048, KZERO, &d0, &R1);
  scan_select(hist2 + b * 2048, 2048, R1, &d1, &R2);
  const unsigned int p22 = ((unsigned int)d0 << 11) | (unsigned int)d1;
  __shared__ unsigned int lh[1024];
  for (int k = t; k < 1024; k += 256) lh[k] = 0u;
  __syncthreads();
  const uint4* base = (const uint4*)adju + (size_t)b * QPS;
  const int qend = (part + 1) * QPB;
  for (int q = part * QPB + t; q < qend; q += 256) {
    uint4 u = base[q];
    unsigned int uv[4] = {u.x, u.y, u.z, u.w};
#pragma unroll
    for (int k = 0; k < 4; ++k) {
      unsigned int uu = uv[k];
      if ((uu >> 10) == p22) {
        atomicAdd(&lh[uu & 1023u], 1u);
        unsigned int pos = atomicAdd(&stNC[b], 1u);
        if (pos < CANDCAP) {
          candI[b * CANDCAP + pos] = (unsigned int)(q * 4 + k);
          candU[b * CANDCAP + pos] = uu;
        }
      }
    }
  }
  __syncthreads();
  for (int k = t; k < 1024; k += 256)
    if (lh[k]) atomicAdd(&hist3[b * 1024 + k], lh[k]);
}

// per-sample: derive T, resolve stable tie index
__global__ __launch_bounds__(256) void k_scanF(const unsigned int* __restrict__ hist0,
                                               const unsigned int* __restrict__ hist2,
                                               const unsigned int* __restrict__ hist3,
                                               const unsigned int* __restrict__ stNC,
                                               const unsigned int* __restrict__ candI,
                                               const unsigned int* __restrict__ candU,
                                               unsigned int* __restrict__ stT,
                                               int* __restrict__ stIdxT) {
  const int b = blockIdx.x, t = threadIdx.x;
  int d0, d1, d2; unsigned int R1, R2, R3;
  scan_select(hist0 + b * 2048, 2048, KZERO, &d0, &R1);
  scan_select(hist2 + b * 2048, 2048, R1, &d1, &R2);
  scan_select(hist3 + b * 1024, 1024, R2, &d2, &R3);
  const unsigned int T = ((((unsigned int)d0 << 11) | (unsigned int)d1) << 10)
                         | (unsigned int)d2;
  if (t == 0) stT[b] = T;
  int nc = (int)stNC[b];
  if (nc > CANDCAP) nc = CANDCAP;
  for (int i = t; i < nc; i += 256) {
    if (candU[b * CANDCAP + i] != T) continue;
    unsigned int my = candI[b * CANDCAP + i];
    unsigned int rank = 0;
    for (int j = 0; j < nc; ++j)
      rank += (unsigned)(candU[b * CANDCAP + j] == T &&
                         candI[b * CANDCAP + j] < my);
    if (rank == R3) stIdxT[b] = (int)my;
  }
}

// final rewrite (skip stores for all-kept quads)
__global__ __launch_bounds__(256) void k_final(unsigned int* __restrict__ adju,
                                               const unsigned int* __restrict__ stT,
                                               const int* __restrict__ stIdxT) {
  const int blk = blockIdx.x, b = blk / BPS, part = blk % BPS, t = threadIdx.x;
  const unsigned int T = stT[b];
  const int idxT = stIdxT[b];
  uint4* base = (uint4*)adju + (size_t)b * QPS;
  const int qend = (part + 1) * QPB;
  for (int q = part * QPB + t; q < qend; q += 256) {
    uint4 u = base[q];
    int e0 = q * 4;
    uint4 v;
    v.x = (u.x < T || (u.x == T && (e0 + 0) < idxT)) ? 0u : u.x;
    v.y = (u.y < T || (u.y == T && (e0 + 1) < idxT)) ? 0u : u.y;
    v.z = (u.z < T || (u.z == T && (e0 + 2) < idxT)) ? 0u : u.z;
    v.w = (u.w < T || (u.w == T && (e0 + 3) < idxT)) ? 0u : u.w;
    if (v.x != u.x || v.y != u.y || v.z != u.z || v.w != u.w) base[q] = v;
  }
}

extern "C" void kernel_launch(void* const* d_in, const int* in_sizes, int n_in,
                              void* d_out, int out_size, void* d_ws, size_t ws_size,
                              hipStream_t stream) {
  const float* x = (const float*)d_in[0];
  float* out0 = (float*)d_out;                       // xf: 26,214,400 floats
  unsigned int* adju = (unsigned int*)((float*)d_out + (size_t)26214400);

  char* ws = (char*)d_ws;
  float* glb = (float*)(ws + 0);                        // 204800 B
  float* mx  = (float*)(ws + 204800);                   // 204800 B
  unsigned int* hist0 = (unsigned int*)(ws + 409600);   // 128*2048*4 = 1 MB
  unsigned int* hist2 = (unsigned int*)(ws + 1458176);  // 1 MB
  unsigned int* hist3 = (unsigned int*)(ws + 2506752);  // 512 KB
  unsigned int* stNC  = (unsigned int*)(ws + 3031040);  // 512 B
  unsigned int* stT   = (unsigned int*)(ws + 3031552);  // 512 B
  int*          stIdxT= (int*)(ws + 3032064);           // 512 B
  unsigned int* candI = (unsigned int*)(ws + 3032576);  // 256 KB
  unsigned int* candU = (unsigned int*)(ws + 3294720);  // 256 KB (ends ~3.4 MB)
  unsigned int* zbase = hist0;
  const int zwords = (3032576 - 409600) / 4;            // hist0..stIdxT

  k_pool<<<NROWS / 4, 256, 0, stream>>>(x, out0, glb, mx, zbase, zwords);
  k_sig<<<NSAMP * BPS, 256, 0, stream>>>(glb, mx, adju, hist0);
  k_hist1<<<NSAMP * BPS, 256, 0, stream>>>(adju, hist0, hist2);
  k_hist2<<<NSAMP * BPS, 256, 0, stream>>>(adju, hist0, hist2, hist3, stNC, candI, candU);
  k_scanF<<<NSAMP, 256, 0, stream>>>(hist0, hist2, hist3, stNC, candI, candU, stT, stIdxT);
  k_final<<<NSAMP * BPS, 256, 0, stream>>>(adju, stT, stIdxT);
}

// Round 21
// 121.765 us; speedup vs baseline: 3.3583x; 1.4361x over previous
//
#include <hip/hip_runtime.h>
#include <math.h>

#define HDIM  512
#define NSAMP 128
#define NN    400
#define NN2   160000  // 400*400
#define KZERO 48000   // int(400*400*30/100)
#define NROWS 51200   // 128*400
#define BPS   10      // blocks per sample in element-sweep kernels
#define QPS   40000   // uint4 quads per sample
#define QPB   4000    // quads per block
#define NBINS 12288   // linear bins over u in (0x3E000000, 0x3F800000]
#define NWORDS 6144   // NBINS/2 packed u16 pairs
#define BINBASE 0x3E000000u
#define BINSH 11
#define CANDCAP 1024

// ===== FROZEN bit-exact math (verified PASS rounds 18-20) =====
__device__ __forceinline__ float xla_expf(float x) {
  x = fminf(88.3762626647950f, fmaxf(-88.3762626647949f, x));
  float fx = floorf(fmaf(x, 1.44269504088896341f, 0.5f));
  x = fmaf(fx, -0.693359375f, x);
  x = fmaf(fx, 2.12194440e-4f, x);
  float z2 = __fmul_rn(x, x);
  float y = 1.9875691500e-4f;
  y = fmaf(y, x, 1.3981999507e-3f);
  y = fmaf(y, x, 8.3334519073e-3f);
  y = fmaf(y, x, 4.1665795894e-2f);
  y = fmaf(y, x, 1.6666665459e-1f);
  y = fmaf(y, x, 5.0000001201e-1f);
  y = fmaf(y, z2, x);
  y = __fadd_rn(y, 1.0f);
  int n = (int)fx;
  float p2n = __int_as_float((n + 127) << 23);
  return __fmul_rn(y, p2n);
}

__device__ __forceinline__ float sigf(float g, float m) {
  float z = __fmul_rn(g, m);
  float e = xla_expf(-z);
  float den = __fadd_rn(1.0f, e);
  return __fdiv_rn(1.0f, den);
}

// order-preserving linear bin over the sigmoid's f32 bits
__device__ __forceinline__ int binOf(unsigned int u) {
  if (u < BINBASE) return 0;
  unsigned int d = (u - BINBASE) >> BINSH;
  return d > (NBINS - 1) ? (NBINS - 1) : (int)d;
}

// k_pool: FROZEN math (copy + order-free max + VF8xIC1 mean) + zero hist/state.
__global__ __launch_bounds__(256) void k_pool(const float* __restrict__ x,
                                              float* __restrict__ out0,
                                              float* __restrict__ glb,
                                              float* __restrict__ mx,
                                              unsigned int* __restrict__ zbase,
                                              int zwords) {
  int gid = blockIdx.x * 256 + threadIdx.x;
  if (gid < zwords) zbase[gid] = 0u;
  __shared__ float buf[4][512];
  const int wave = threadIdx.x >> 6;
  const int lane = threadIdx.x & 63;
  const int row  = blockIdx.x * 4 + wave;
  const float4* xr = reinterpret_cast<const float4*>(x) + (size_t)row * 128;
  float4* o = reinterpret_cast<float4*>(out0) + (size_t)row * 128;
  float4 a = xr[lane];
  float4 b = xr[lane + 64];
  o[lane]      = a;
  o[lane + 64] = b;
  reinterpret_cast<float4*>(buf[wave])[lane]      = a;
  reinterpret_cast<float4*>(buf[wave])[lane + 64] = b;
  float m = fmaxf(fmaxf(fmaxf(a.x, a.y), fmaxf(a.z, a.w)),
                  fmaxf(fmaxf(b.x, b.y), fmaxf(b.z, b.w)));
#pragma unroll
  for (int off = 32; off > 0; off >>= 1) m = fmaxf(m, __shfl_xor(m, off));
  __syncthreads();
  float r = 0.0f;
  if (lane < 8) {
    const float* p = buf[wave] + lane;
    r = p[0];
    for (int t = 1; t < 64; ++t) r = __fadd_rn(r, p[8 * t]);
    r = __fadd_rn(r, __shfl_xor(r, 4));
    r = __fadd_rn(r, __shfl_xor(r, 2));
    r = __fadd_rn(r, __shfl_xor(r, 1));
  }
  if (lane == 0) {
    glb[row] = __fmul_rn(r, 0.001953125f);
    mx[row]  = m;
  }
}

// k_sig: compute each sigmoid ONCE, store bits to adj, build the packed
// 12288-bin histogram in LDS (u16 pairs, 24 KB) and merge to global.
__global__ __launch_bounds__(256) void k_sig(const float* __restrict__ glb,
                                             const float* __restrict__ mx,
                                             unsigned int* __restrict__ adju,
                                             unsigned int* __restrict__ hist) {
  const int blk = blockIdx.x, b = blk / BPS, part = blk % BPS, t = threadIdx.x;
  __shared__ unsigned int lh[NWORDS];
  for (int k = t; k < NWORDS; k += 256) lh[k] = 0u;
  __syncthreads();
  const float* gb = glb + b * NN;
  const float4* mb = (const float4*)(mx + b * NN);
  uint4* base = (uint4*)adju + (size_t)b * QPS;
  const int qend = (part + 1) * QPB;
  for (int q = part * QPB + t; q < qend; q += 256) {
    int i  = q / 100;            // 100 float4 per row
    int jq = q - i * 100;
    float g = gb[i];
    float4 m4 = mb[jq];
    uint4 u;
    u.x = __float_as_uint(sigf(g, m4.x));
    u.y = __float_as_uint(sigf(g, m4.y));
    u.z = __float_as_uint(sigf(g, m4.z));
    u.w = __float_as_uint(sigf(g, m4.w));
    base[q] = u;
    int b0 = binOf(u.x), b1 = binOf(u.y), b2 = binOf(u.z), b3 = binOf(u.w);
    atomicAdd(&lh[b0 >> 1], 1u << ((b0 & 1) << 4));
    atomicAdd(&lh[b1 >> 1], 1u << ((b1 & 1) << 4));
    atomicAdd(&lh[b2 >> 1], 1u << ((b2 & 1) << 4));
    atomicAdd(&lh[b3 >> 1], 1u << ((b3 & 1) << 4));
  }
  __syncthreads();
  unsigned int* gh = hist + (size_t)b * NWORDS;
  for (int k = t; k < NWORDS; k += 256)
    if (lh[k]) atomicAdd(&gh[k], lh[k]);
}

// k_scanBin: per sample, find bin B containing rank KZERO and rank-in-bin R.
__global__ __launch_bounds__(256) void k_scanBin(const unsigned int* __restrict__ hist,
                                                 unsigned int* __restrict__ stB,
                                                 unsigned int* __restrict__ stR) {
  const int b = blockIdx.x, t = threadIdx.x;
  const unsigned int* h = hist + (size_t)b * NWORDS;
  unsigned int w[24];
  unsigned int part = 0;
  for (int k = 0; k < 24; ++k) {
    w[k] = h[t * 24 + k];
    part += (w[k] & 0xffffu) + (w[k] >> 16);
  }
  const int lane = t & 63, wid = t >> 6;
  unsigned int inc = part;
  for (int off = 1; off < 64; off <<= 1) {
    unsigned int v = __shfl_up(inc, off);
    if (lane >= off) inc += v;
  }
  __shared__ unsigned int wsum[4], wbase[4];
  __shared__ int sB;
  __shared__ unsigned int sR;
  if (lane == 63) wsum[wid] = inc;
  __syncthreads();
  if (t == 0) {
    unsigned int c = 0;
    for (int i = 0; i < 4; ++i) { wbase[i] = c; c += wsum[i]; }
  }
  __syncthreads();
  unsigned int excl = wbase[wid] + inc - part;
  if (part > 0 && KZERO >= excl && KZERO < excl + part) {
    unsigned int c = excl;
    for (int k = 0; k < 24; ++k) {
      unsigned int lo = w[k] & 0xffffu, hi = w[k] >> 16;
      if ((unsigned)KZERO < c + lo) { sB = (t * 24 + k) * 2;     sR = KZERO - c; break; }
      c += lo;
      if ((unsigned)KZERO < c + hi) { sB = (t * 24 + k) * 2 + 1; sR = KZERO - c; break; }
      c += hi;
    }
  }
  __syncthreads();
  if (t == 0) { stB[b] = (unsigned int)sB; stR[b] = sR; }
}

// k_cand: sweep adj, collect all elements in bin B (index, bits).
__global__ __launch_bounds__(256) void k_cand(const unsigned int* __restrict__ adju,
                                              const unsigned int* __restrict__ stB,
                                              unsigned int* __restrict__ stNC,
                                              unsigned int* __restrict__ candI,
                                              unsigned int* __restrict__ candU) {
  const int blk = blockIdx.x, b = blk / BPS, part = blk % BPS, t = threadIdx.x;
  const int B = (int)stB[b];
  const uint4* base = (const uint4*)adju + (size_t)b * QPS;
  const int qend = (part + 1) * QPB;
  for (int q = part * QPB + t; q < qend; q += 256) {
    uint4 u = base[q];
    unsigned int uv[4] = {u.x, u.y, u.z, u.w};
#pragma unroll
    for (int k = 0; k < 4; ++k) {
      if (binOf(uv[k]) == B) {
        unsigned int pos = atomicAdd(&stNC[b], 1u);
        if (pos < CANDCAP) {
          candI[b * CANDCAP + pos] = (unsigned int)(q * 4 + k);
          candU[b * CANDCAP + pos] = uv[k];
        }
      }
    }
  }
}

// k_final: redundantly resolve (T, idxT) from candidates (deterministic),
// then sweep-zero. Zero rule identical to rounds 18-20.
__global__ __launch_bounds__(256) void k_final(unsigned int* __restrict__ adju,
                                               const unsigned int* __restrict__ stR,
                                               const unsigned int* __restrict__ stNC,
                                               const unsigned int* __restrict__ candI,
                                               const unsigned int* __restrict__ candU) {
  const int blk = blockIdx.x, b = blk / BPS, part = blk % BPS, t = threadIdx.x;
  __shared__ unsigned int cI[CANDCAP], cU[CANDCAP];
  __shared__ unsigned int sT, sIdx;
  int nc = (int)stNC[b];
  if (nc > CANDCAP) nc = CANDCAP;
  for (int i = t; i < nc; i += 256) {
    cI[i] = candI[b * CANDCAP + i];
    cU[i] = candU[b * CANDCAP + i];
  }
  if (t == 0) { sT = 0xFFFFFFFFu; sIdx = 0u; }
  __syncthreads();
  const unsigned int R = stR[b];
  for (int i = t; i < nc; i += 256) {
    unsigned int ui = cU[i], ii = cI[i];
    unsigned int rank = 0;
    for (int j = 0; j < nc; ++j)
      rank += (unsigned)((cU[j] < ui) || (cU[j] == ui && cI[j] < ii));
    if (rank == R) { sT = ui; sIdx = ii; }
  }
  __syncthreads();
  const unsigned int T = sT;
  const int idxT = (int)sIdx;
  uint4* base = (uint4*)adju + (size_t)b * QPS;
  const int qend = (part + 1) * QPB;
  for (int q = part * QPB + t; q < qend; q += 256) {
    uint4 u = base[q];
    int e0 = q * 4;
    uint4 v;
    v.x = (u.x < T || (u.x == T && (e0 + 0) < idxT)) ? 0u : u.x;
    v.y = (u.y < T || (u.y == T && (e0 + 1) < idxT)) ? 0u : u.y;
    v.z = (u.z < T || (u.z == T && (e0 + 2) < idxT)) ? 0u : u.z;
    v.w = (u.w < T || (u.w == T && (e0 + 3) < idxT)) ? 0u : u.w;
    if (v.x != u.x || v.y != u.y || v.z != u.z || v.w != u.w) base[q] = v;
  }
}

extern "C" void kernel_launch(void* const* d_in, const int* in_sizes, int n_in,
                              void* d_out, int out_size, void* d_ws, size_t ws_size,
                              hipStream_t stream) {
  const float* x = (const float*)d_in[0];
  float* out0 = (float*)d_out;                       // xf: 26,214,400 floats
  unsigned int* adju = (unsigned int*)((float*)d_out + (size_t)26214400);

  char* ws = (char*)d_ws;
  float* glb = (float*)(ws + 0);                        // 204800 B
  float* mx  = (float*)(ws + 204800);                   // 204800 B
  unsigned int* hist = (unsigned int*)(ws + 409600);    // 128*6144*4 = 3,145,728 B
  unsigned int* stNC = (unsigned int*)(ws + 3555328);   // 512 B (contiguous w/ hist for zeroing)
  unsigned int* stB  = (unsigned int*)(ws + 3555840);   // 512 B
  unsigned int* stR  = (unsigned int*)(ws + 3556352);   // 512 B
  unsigned int* candI = (unsigned int*)(ws + 3556864);  // 128*1024*4 = 512 KB
  unsigned int* candU = (unsigned int*)(ws + 4081152);  // 512 KB (ends ~4.6 MB)
  unsigned int* zbase = hist;
  const int zwords = (3555840 - 409600) / 4;            // hist + stNC

  k_pool<<<NROWS / 4, 256, 0, stream>>>(x, out0, glb, mx, zbase, zwords);
  k_sig<<<NSAMP * BPS, 256, 0, stream>>>(glb, mx, adju, hist);
  k_scanBin<<<NSAMP, 256, 0, stream>>>(hist, stB, stR);
  k_cand<<<NSAMP * BPS, 256, 0, stream>>>(adju, stB, stNC, candI, candU);
  k_final<<<NSAMP * BPS, 256, 0, stream>>>(adju, stR, stNC, candI, candU);
}

// Round 22
// 110.786 us; speedup vs baseline: 3.6911x; 1.0991x over previous
//
#include <hip/hip_runtime.h>
#include <math.h>

#define HDIM  512
#define NSAMP 128
#define NN    400
#define NN2   160000  // 400*400
#define KZERO 48000   // int(400*400*30/100)
#define NROWS 51200   // 128*400
#define BPS   10      // blocks per sample in element-sweep kernels
#define QPS   40000   // uint4 quads per sample
#define QPB   4000    // quads per block
#define NBINS 12288   // linear bins over u in (0x3E000000, 0x3F800000]
#define NWORDS 6144   // NBINS/2 packed u16 pairs
#define BINBASE 0x3E000000u
#define BINSH 11
#define CANDCAP 1024

// ===== FROZEN bit-exact math (verified PASS rounds 18-21) =====
__device__ __forceinline__ float xla_expf(float x) {
  x = fminf(88.3762626647950f, fmaxf(-88.3762626647949f, x));
  float fx = floorf(fmaf(x, 1.44269504088896341f, 0.5f));
  x = fmaf(fx, -0.693359375f, x);
  x = fmaf(fx, 2.12194440e-4f, x);
  float z2 = __fmul_rn(x, x);
  float y = 1.9875691500e-4f;
  y = fmaf(y, x, 1.3981999507e-3f);
  y = fmaf(y, x, 8.3334519073e-3f);
  y = fmaf(y, x, 4.1665795894e-2f);
  y = fmaf(y, x, 1.6666665459e-1f);
  y = fmaf(y, x, 5.0000001201e-1f);
  y = fmaf(y, z2, x);
  y = __fadd_rn(y, 1.0f);
  int n = (int)fx;
  float p2n = __int_as_float((n + 127) << 23);
  return __fmul_rn(y, p2n);
}

__device__ __forceinline__ float sigf(float g, float m) {
  float z = __fmul_rn(g, m);
  float e = xla_expf(-z);
  float den = __fadd_rn(1.0f, e);
  return __fdiv_rn(1.0f, den);
}

// order-preserving linear bin over the sigmoid's f32 bits
__device__ __forceinline__ int binOf(unsigned int u) {
  if (u < BINBASE) return 0;
  unsigned int d = (u - BINBASE) >> BINSH;
  return d > (NBINS - 1) ? (NBINS - 1) : (int)d;
}

// k_pool: FROZEN math (copy + order-free max + VF8xIC1 mean) + zero hist/state.
__global__ __launch_bounds__(256) void k_pool(const float* __restrict__ x,
                                              float* __restrict__ out0,
                                              float* __restrict__ glb,
                                              float* __restrict__ mx,
                                              unsigned int* __restrict__ zbase,
                                              int zwords) {
  int gid = blockIdx.x * 256 + threadIdx.x;
  if (gid < zwords) zbase[gid] = 0u;
  __shared__ float buf[4][512];
  const int wave = threadIdx.x >> 6;
  const int lane = threadIdx.x & 63;
  const int row  = blockIdx.x * 4 + wave;
  const float4* xr = reinterpret_cast<const float4*>(x) + (size_t)row * 128;
  float4* o = reinterpret_cast<float4*>(out0) + (size_t)row * 128;
  float4 a = xr[lane];
  float4 b = xr[lane + 64];
  o[lane]      = a;
  o[lane + 64] = b;
  reinterpret_cast<float4*>(buf[wave])[lane]      = a;
  reinterpret_cast<float4*>(buf[wave])[lane + 64] = b;
  float m = fmaxf(fmaxf(fmaxf(a.x, a.y), fmaxf(a.z, a.w)),
                  fmaxf(fmaxf(b.x, b.y), fmaxf(b.z, b.w)));
#pragma unroll
  for (int off = 32; off > 0; off >>= 1) m = fmaxf(m, __shfl_xor(m, off));
  __syncthreads();
  float r = 0.0f;
  if (lane < 8) {
    const float* p = buf[wave] + lane;
    r = p[0];
    for (int t = 1; t < 64; ++t) r = __fadd_rn(r, p[8 * t]);
    r = __fadd_rn(r, __shfl_xor(r, 4));
    r = __fadd_rn(r, __shfl_xor(r, 2));
    r = __fadd_rn(r, __shfl_xor(r, 1));
  }
  if (lane == 0) {
    glb[row] = __fmul_rn(r, 0.001953125f);
    mx[row]  = m;
  }
}

// k_sig: compute each sigmoid ONCE, store bits to adj, build the packed
// 12288-bin histogram in LDS (u16 pairs, 24 KB) and merge to global.
__global__ __launch_bounds__(256) void k_sig(const float* __restrict__ glb,
                                             const float* __restrict__ mx,
                                             unsigned int* __restrict__ adju,
                                             unsigned int* __restrict__ hist) {
  const int blk = blockIdx.x, b = blk / BPS, part = blk % BPS, t = threadIdx.x;
  __shared__ unsigned int lh[NWORDS];
  for (int k = t; k < NWORDS; k += 256) lh[k] = 0u;
  __syncthreads();
  const float* gb = glb + b * NN;
  const float4* mb = (const float4*)(mx + b * NN);
  uint4* base = (uint4*)adju + (size_t)b * QPS;
  const int qend = (part + 1) * QPB;
  for (int q = part * QPB + t; q < qend; q += 256) {
    int i  = q / 100;            // 100 float4 per row
    int jq = q - i * 100;
    float g = gb[i];
    float4 m4 = mb[jq];
    uint4 u;
    u.x = __float_as_uint(sigf(g, m4.x));
    u.y = __float_as_uint(sigf(g, m4.y));
    u.z = __float_as_uint(sigf(g, m4.z));
    u.w = __float_as_uint(sigf(g, m4.w));
    base[q] = u;
    int b0 = binOf(u.x), b1 = binOf(u.y), b2 = binOf(u.z), b3 = binOf(u.w);
    atomicAdd(&lh[b0 >> 1], 1u << ((b0 & 1) << 4));
    atomicAdd(&lh[b1 >> 1], 1u << ((b1 & 1) << 4));
    atomicAdd(&lh[b2 >> 1], 1u << ((b2 & 1) << 4));
    atomicAdd(&lh[b3 >> 1], 1u << ((b3 & 1) << 4));
  }
  __syncthreads();
  unsigned int* gh = hist + (size_t)b * NWORDS;
  for (int k = t; k < NWORDS; k += 256)
    if (lh[k]) atomicAdd(&gh[k], lh[k]);
}

// scan_bin: 256-thread parallel select over the packed per-sample histogram:
// bin B containing global rank KZERO, and R = KZERO - cum(<B). Deterministic,
// safe to run redundantly in every block. Contains its own barriers.
__device__ __forceinline__ void scan_bin(const unsigned int* __restrict__ h,
                                         int* B_out, unsigned int* R_out) {
  const int t = threadIdx.x;
  const int lane = t & 63, wid = t >> 6;
  unsigned int w[24];
  unsigned int part = 0;
#pragma unroll
  for (int k = 0; k < 24; ++k) {
    w[k] = h[t * 24 + k];
    part += (w[k] & 0xffffu) + (w[k] >> 16);
  }
  unsigned int inc = part;
  for (int off = 1; off < 64; off <<= 1) {
    unsigned int v = __shfl_up(inc, off);
    if (lane >= off) inc += v;
  }
  __shared__ unsigned int wsum[4], wbase[4];
  __shared__ int sB;
  __shared__ unsigned int sR;
  __syncthreads();
  if (lane == 63) wsum[wid] = inc;
  __syncthreads();
  if (t == 0) {
    unsigned int c = 0;
    for (int i = 0; i < 4; ++i) { wbase[i] = c; c += wsum[i]; }
  }
  __syncthreads();
  unsigned int excl = wbase[wid] + inc - part;
  if (part > 0 && KZERO >= excl && KZERO < excl + part) {
    unsigned int c = excl;
    for (int k = 0; k < 24; ++k) {
      unsigned int lo = w[k] & 0xffffu, hi = w[k] >> 16;
      if ((unsigned)KZERO < c + lo) { sB = (t * 24 + k) * 2;     sR = KZERO - c; break; }
      c += lo;
      if ((unsigned)KZERO < c + hi) { sB = (t * 24 + k) * 2 + 1; sR = KZERO - c; break; }
      c += hi;
    }
  }
  __syncthreads();
  *B_out = sB;
  *R_out = sR;
}

// k_candzero: ONE sweep. bin<B -> zero; bin>B -> keep; bin==B -> record
// candidate, leave value (k_fix zeroes the below-cutoff ones).
__global__ __launch_bounds__(256) void k_candzero(unsigned int* __restrict__ adju,
                                                  const unsigned int* __restrict__ hist,
                                                  unsigned int* __restrict__ stNC,
                                                  unsigned int* __restrict__ candI,
                                                  unsigned int* __restrict__ candU) {
  const int blk = blockIdx.x, b = blk / BPS, part = blk % BPS, t = threadIdx.x;
  int B; unsigned int R;
  scan_bin(hist + (size_t)b * NWORDS, &B, &R);
  uint4* base = (uint4*)adju + (size_t)b * QPS;
  const int qend = (part + 1) * QPB;
  for (int q = part * QPB + t; q < qend; q += 256) {
    uint4 u = base[q];
    int b0 = binOf(u.x), b1 = binOf(u.y), b2 = binOf(u.z), b3 = binOf(u.w);
    uint4 v = u;
    if (b0 < B) v.x = 0u;
    if (b1 < B) v.y = 0u;
    if (b2 < B) v.z = 0u;
    if (b3 < B) v.w = 0u;
    if (b0 == B) { unsigned int p = atomicAdd(&stNC[b], 1u);
      if (p < CANDCAP) { candI[b * CANDCAP + p] = (unsigned)(q * 4 + 0); candU[b * CANDCAP + p] = u.x; } }
    if (b1 == B) { unsigned int p = atomicAdd(&stNC[b], 1u);
      if (p < CANDCAP) { candI[b * CANDCAP + p] = (unsigned)(q * 4 + 1); candU[b * CANDCAP + p] = u.y; } }
    if (b2 == B) { unsigned int p = atomicAdd(&stNC[b], 1u);
      if (p < CANDCAP) { candI[b * CANDCAP + p] = (unsigned)(q * 4 + 2); candU[b * CANDCAP + p] = u.z; } }
    if (b3 == B) { unsigned int p = atomicAdd(&stNC[b], 1u);
      if (p < CANDCAP) { candI[b * CANDCAP + p] = (unsigned)(q * 4 + 3); candU[b * CANDCAP + p] = u.w; } }
    if (v.x != u.x || v.y != u.y || v.z != u.z || v.w != u.w) base[q] = v;
  }
}

// k_fix: per sample, rank the ~93 bin-B candidates by (u, idx) (stable rule)
// and zero those with rank < R (positions 0..R-1 of the sorted tie window).
__global__ __launch_bounds__(256) void k_fix(unsigned int* __restrict__ adju,
                                             const unsigned int* __restrict__ hist,
                                             const unsigned int* __restrict__ stNC,
                                             const unsigned int* __restrict__ candI,
                                             const unsigned int* __restrict__ candU) {
  const int b = blockIdx.x, t = threadIdx.x;
  int B; unsigned int R;
  scan_bin(hist + (size_t)b * NWORDS, &B, &R);
  __shared__ unsigned int cI[CANDCAP], cU[CANDCAP];
  int nc = (int)stNC[b];
  if (nc > CANDCAP) nc = CANDCAP;
  for (int i = t; i < nc; i += 256) {
    cI[i] = candI[b * CANDCAP + i];
    cU[i] = candU[b * CANDCAP + i];
  }
  __syncthreads();
  unsigned int* a = adju + (size_t)b * NN2;
  for (int i = t; i < nc; i += 256) {
    unsigned int ui = cU[i], ii = cI[i];
    unsigned int rank = 0;
    for (int j = 0; j < nc; ++j)
      rank += (unsigned)((cU[j] < ui) || (cU[j] == ui && cI[j] < ii));
    if (rank < R) a[ii] = 0u;
  }
}

extern "C" void kernel_launch(void* const* d_in, const int* in_sizes, int n_in,
                              void* d_out, int out_size, void* d_ws, size_t ws_size,
                              hipStream_t stream) {
  const float* x = (const float*)d_in[0];
  float* out0 = (float*)d_out;                       // xf: 26,214,400 floats
  unsigned int* adju = (unsigned int*)((float*)d_out + (size_t)26214400);

  char* ws = (char*)d_ws;
  float* glb = (float*)(ws + 0);                        // 204800 B
  float* mx  = (float*)(ws + 204800);                   // 204800 B
  unsigned int* hist = (unsigned int*)(ws + 409600);    // 128*6144*4 = 3,145,728 B
  unsigned int* stNC = (unsigned int*)(ws + 3555328);   // 512 B (contiguous for zeroing)
  unsigned int* candI = (unsigned int*)(ws + 3555840);  // 128*1024*4 = 524,288 B
  unsigned int* candU = (unsigned int*)(ws + 4080128);  // 524,288 B (ends ~4.6 MB)
  unsigned int* zbase = hist;
  const int zwords = (3555840 - 409600) / 4;            // hist + stNC

  k_pool<<<NROWS / 4, 256, 0, stream>>>(x, out0, glb, mx, zbase, zwords);
  k_sig<<<NSAMP * BPS, 256, 0, stream>>>(glb, mx, adju, hist);
  k_candzero<<<NSAMP * BPS, 256, 0, stream>>>(adju, hist, stNC, candI, candU);
  k_fix<<<NSAMP, 256, 0, stream>>>(adju, hist, stNC, candI, candU);
}